// Round 9
// baseline (498.998 us; speedup 1.0000x reference)
//
#include <hip/hip_runtime.h>
#include <cstdint>
#include <cmath>

// Problem constants
#define EDIM 1024
#define SEQ 2048
#define BATCH 4
#define NHEAD 16
#define HDIM 64
#define MLPD 4096
#define ROWS 8192  // BATCH*SEQ

typedef unsigned short u16;
typedef __attribute__((ext_vector_type(8))) short short8;   // 8 bf16 = 4 VGPRs (MFMA A/B frag)
typedef __attribute__((ext_vector_type(4))) float floatx4;  // MFMA C/D frag

#define AS1 __attribute__((address_space(1)))
#define AS3 __attribute__((address_space(3)))

// exp(s*0.125) = 2^(s*0.125*log2e); fold scale into Q at GEMM epilogue
#define Q_SCALE 0.18033688011112042f

__device__ __forceinline__ void async16(const void* g, void* l) {
  // 16B-wide global->LDS DMA; LDS dest is wave-uniform base + lane*16
  __builtin_amdgcn_global_load_lds((AS1 void*)g, (AS3 void*)l, 16, 0, 0);
}

__device__ __forceinline__ u16 f2bf(float f) {  // RNE float->bf16
  union { float f; unsigned int u; } v; v.f = f;
  unsigned int u = v.u;
  u += 0x7fffu + ((u >> 16) & 1u);
  return (u16)(u >> 16);
}

__device__ __forceinline__ unsigned int u32of(float f) {
  union { float f; unsigned int u; } v; v.f = f; return v.u;
}

// pack hi16(a)|hi16(b)<<16 in one v_perm_b32 (truncating f32->bf16 pair)
__device__ __forceinline__ unsigned int pack_trunc(float a, float b) {
  return __builtin_amdgcn_perm(u32of(b), u32of(a), 0x07060302u);
}

// native v_exp_f32: computes 2^x
__device__ __forceinline__ float exp2_fast(float x) {
  return __builtin_amdgcn_exp2f(x);
}

// fast GELU (tanh form), ~12 VALU ops, no libm
__device__ __forceinline__ float gelu_f(float x) {
  const float y = 0.7978845608028654f * (x + 0.044715f * x * x * x);
  // tanh(y) = 1 - 2/(1 + 2^(y*2*log2(e)))
  const float e = exp2_fast(y * 2.885390081777927f);
  const float t = 1.0f - 2.0f * __builtin_amdgcn_rcpf(1.0f + e);
  return 0.5f * x * (1.0f + t);
}

// ---------------- all-weights fp32 -> bf16 convert (one launch) ----------------
// Region boundaries are multiples of 1024 elements -> no intra-block divergence.
__global__ __launch_bounds__(256) void cvt_all(const float* __restrict__ a, u16* __restrict__ oa, int na,
                                               const float* __restrict__ b, u16* __restrict__ ob, int nb,
                                               const float* __restrict__ c, u16* __restrict__ oc, int nc,
                                               const float* __restrict__ d, u16* __restrict__ od) {
  int i = (blockIdx.x * 256 + threadIdx.x) * 4;
  const float* src;
  u16* dst;
  if (i < na) { src = a; dst = oa; }
  else if ((i -= na) < nb) { src = b; dst = ob; }
  else if ((i -= nb) < nc) { src = c; dst = oc; }
  else { i -= nc; src = d; dst = od; }
  const float4 v = *(const float4*)(src + i);
  dst[i + 0] = f2bf(v.x); dst[i + 1] = f2bf(v.y);
  dst[i + 2] = f2bf(v.z); dst[i + 3] = f2bf(v.w);
}

// ---------------- LayerNorm (row of 1024) -> bf16 ----------------
__global__ __launch_bounds__(256) void ln_bf16(const float* __restrict__ x,
                                               const float* __restrict__ g,
                                               const float* __restrict__ bta,
                                               u16* __restrict__ outp) {
  const int row = blockIdx.x;
  const int tid = threadIdx.x;
  const float4 v = *(const float4*)(x + (size_t)row * EDIM + tid * 4);
  float s = v.x + v.y + v.z + v.w;
  float ss = v.x * v.x + v.y * v.y + v.z * v.z + v.w * v.w;
#pragma unroll
  for (int o = 1; o < 64; o <<= 1) {
    s += __shfl_xor(s, o);
    ss += __shfl_xor(ss, o);
  }
  __shared__ float red[8];
  const int wave = tid >> 6, lane = tid & 63;
  if (lane == 0) { red[wave] = s; red[4 + wave] = ss; }
  __syncthreads();
  s = red[0] + red[1] + red[2] + red[3];
  ss = red[4] + red[5] + red[6] + red[7];
  const float mu = s * (1.0f / 1024.0f);
  const float var = ss * (1.0f / 1024.0f) - mu * mu;
  const float inv = rsqrtf(var + 1e-5f);
  const float4 gv = *(const float4*)(g + tid * 4);
  const float4 bv = *(const float4*)(bta + tid * 4);
  u16* od = outp + (size_t)row * EDIM + tid * 4;
  od[0] = f2bf((v.x - mu) * inv * gv.x + bv.x);
  od[1] = f2bf((v.y - mu) * inv * gv.y + bv.y);
  od[2] = f2bf((v.z - mu) * inv * gv.z + bv.z);
  od[3] = f2bf((v.w - mu) * inv * gv.w + bv.w);
}

// ---------------- NT GEMM (proven 2-barrier structure): BMx128, BKx, 8 waves ------
// T1 XCD-affine remap (proven R5: 508->483): all nx col-blocks of one row-panel
// time-adjacent on ONE XCD so the shared A-panel hits that XCD's L2.
// Bijective for gridDim.y%8==0.
// BK=128 (proven R7: 483->480) for the grid-limited 2-block/CU GEMMs (fc, w2):
// halves exposed drain-barrier events at equal residency.
// EPI: 0 = store fp32
//      1/3 = fp32 store of (acc + bias[col] + res[idx])
//      2 = bf16 store of gelu(acc + bias[col])
//      4 = bf16 store of acc
//      5 = bf16 store of acc * (col<1024 ? Q_SCALE : 1)  (qkv GEMM, prescaled Q)
template <int EPI, int BM = 256, int BK = 64>
__global__ __launch_bounds__(512) void gemm_bt(const u16* __restrict__ A,
                                               const u16* __restrict__ Bw,
                                               void* __restrict__ Cout,
                                               const float* __restrict__ bias,
                                               const float* __restrict__ res,
                                               int M, int N, int K) {
  constexpr int IB = BM / 64;        // acc rows per wave: 256->4, 128->2
  constexpr int WROWS = BM / 4;      // rows per wave band: 256->64, 128->32
  constexpr int CPR = BK / 8;        // 16B chunks per row: 8 (BK=64) / 16 (BK=128)
  constexpr int ROWSP = 512 / CPR;   // rows staged per pass: 64 / 32
  constexpr int PA = BM / ROWSP;     // A staging passes
  constexpr int PB = 128 / ROWSP;    // B staging passes
  constexpr int S = BK / 32;         // k sub-steps per tile: 2 / 4
  __shared__ __align__(16) u16 As[BM * BK];
  __shared__ __align__(16) u16 Bs[128 * BK];
  const int tid = threadIdx.x;
  const int lane = tid & 63;
  const int wave = tid >> 6;      // 0..7
  const int quad = lane >> 4;
  const int cl = lane & 15;

  // ---- T1: XCD-affine bijective block remap (requires gridDim.y % 8 == 0) ----
  const int nx = gridDim.x;
  const int f = blockIdx.y * nx + blockIdx.x;   // dispatch-linear id
  const int xcd = f & 7;                        // HW round-robin XCD
  const int uu = f >> 3;
  const int rows_per = gridDim.y >> 3;          // row-panels per XCD
  const int bxy = xcd * rows_per + uu / nx;     // row-panel (col-blocks adjacent)
  const int bxx = uu % nx;                      // col-block

  const int row0 = bxy * BM;
  const int col0 = bxx * 128;
  const int wm = wave >> 1;       // 0..3: WROWS-row band
  const int wn = wave & 1;        // 0..1: 64-col band

  floatx4 acc[IB][4];
#pragma unroll
  for (int i = 0; i < IB; ++i)
#pragma unroll
    for (int j = 0; j < 4; ++j) acc[i][j] = (floatx4){0.f, 0.f, 0.f, 0.f};

  // staging: chunk c = p*512 + tid; row = p*ROWSP + (tid/CPR); LDS slot = tid%CPR;
  // global chunk gc = (tid%CPR) ^ (row&7)  (p-independent since ROWSP%8==0).
  const int trow = tid / CPR;
  const int gc = (tid % CPR) ^ (trow & 7);
  const u16* Ath = A + (size_t)(row0 + trow) * K + gc * 8;
  const u16* Bth = Bw + (size_t)(col0 + trow) * K + gc * 8;
  u16* lA = As + tid * 8;                  // + p*4096
  u16* lB = Bs + tid * 8;
  const size_t pstride = (size_t)ROWSP * K;

  for (int k0 = 0; k0 < K; k0 += BK) {
    __syncthreads();
#pragma unroll
    for (int p = 0; p < PA; ++p)
      async16(Ath + p * pstride + k0, lA + p * 4096);
#pragma unroll
    for (int p = 0; p < PB; ++p)
      async16(Bth + p * pstride + k0, lB + p * 4096);
    __syncthreads();
#pragma unroll
    for (int s = 0; s < S; ++s) {
      const int ko = ((s * 4 + quad) ^ (cl & 7)) * 8;
      short8 af[IB], bfr[4];
#pragma unroll
      for (int i = 0; i < IB; ++i)
        af[i] = *(const short8*)(As + (wm * WROWS + i * 16 + cl) * BK + ko);
#pragma unroll
      for (int j = 0; j < 4; ++j)
        bfr[j] = *(const short8*)(Bs + (wn * 64 + j * 16 + cl) * BK + ko);
#pragma unroll
      for (int i = 0; i < IB; ++i)
#pragma unroll
        for (int j = 0; j < 4; ++j)
          acc[i][j] = __builtin_amdgcn_mfma_f32_16x16x32_bf16(af[i], bfr[j], acc[i][j], 0, 0, 0);
    }
  }

  const float qscale = (EPI == 5 && col0 < 1024) ? Q_SCALE : 1.0f;
#pragma unroll
  for (int i = 0; i < IB; ++i) {
#pragma unroll
    for (int r = 0; r < 4; ++r) {
      const int row = row0 + wm * WROWS + i * 16 + quad * 4 + r;
#pragma unroll
      for (int j = 0; j < 4; ++j) {
        const int col = col0 + wn * 64 + j * 16 + cl;
        const size_t idx = (size_t)row * N + col;
        float v = acc[i][j][r];
        if (EPI == 0) {
          ((float*)Cout)[idx] = v;
        } else if (EPI == 1 || EPI == 3) {
          ((float*)Cout)[idx] = v + bias[col] + res[idx];
        } else if (EPI == 2) {
          ((u16*)Cout)[idx] = f2bf(gelu_f(v + bias[col]));
        } else if (EPI == 4) {
          ((u16*)Cout)[idx] = f2bf(v);
        } else if (EPI == 5) {
          ((u16*)Cout)[idx] = f2bf(v * qscale);
        }
      }
    }
  }
}

// ---------------- V transpose: qkv bf16 [tok][3072] -> vt[b,h][d][s] bf16 ----------------
__global__ __launch_bounds__(256) void vtrans(const u16* __restrict__ qkv,
                                              u16* __restrict__ vt) {
  __shared__ unsigned int T[64 * 65];
  const int tid = threadIdx.x;
  const int bh = blockIdx.y;
  const int b = bh >> 4;
  const int h = bh & 15;
  const int s0 = blockIdx.x * 64;
#pragma unroll
  for (int pp = 0; pp < 2; ++pp) {
    const int g = pp * 256 + tid;
    const int r = g >> 3;
    const int d0 = (g & 7) * 8;
    const u16* src = qkv + (size_t)(b * SEQ + s0 + r) * 3072 + 2048 + h * 64 + d0;
    short8 v = *(const short8*)src;
#pragma unroll
    for (int i = 0; i < 8; ++i) T[(d0 + i) * 65 + r] = (u16)v[i];
  }
  __syncthreads();
#pragma unroll
  for (int pp = 0; pp < 2; ++pp) {
    const int g = pp * 256 + tid;
    const int d = g >> 3;
    const int sc = (g & 7) * 8;
    short8 v;
#pragma unroll
    for (int i = 0; i < 8; ++i) v[i] = (short)(u16)T[d * 65 + sc + i];
    *(short8*)(vt + ((size_t)bh * 64 + d) * SEQ + s0 + sc) = v;
  }
}

// ---------------- MFMA flash attention v3.2 ----------------
// v3.1 (proven R8: attn 112.8->104.3): l on the matrix pipe via mfma(ones, pf).
// v3.2 (this round): TAIL ELIMINATION. Was: 1024 blocks at 3/CU -> 768 resident
// + 256-block tail at 1/CU (measured Occupancy ~19% vs 37.5% cap). Now: each
// block processes TWO consecutive q-tiles serially -> 512 blocks at 2/CU, whole
// grid co-resident, 8 waves/CU continuously. Mixed latency/throughput model:
// old = max(L,3D)+max(L,D), new = max(2L,4D) -> ~10-20% win in the mid-regime.
// Per-substep code, LDS layout, and all index math inside the kt loop UNCHANGED;
// the half-loop top barrier guards Q re-staging over the consumed Ks region.
__global__ __launch_bounds__(256, 4) void attn3(const u16* __restrict__ qkv,
                                                const u16* __restrict__ vt,
                                                u16* __restrict__ outp) {
  __shared__ __align__(16) u16 smem[8192 + 8192 + 4 * 32 * 72];  // Ks | Vs | P (51.2 KB)
  u16* Ks = smem;            // [128 kv][64 d], chunk-swizzled ^(row&7)
  u16* Vs = smem + 8192;     // [64 d][128 kv], chunk-swizzled ^(row&15)
  const int tid = threadIdx.x;
  const int lane = tid & 63;
  const int wave = tid >> 6;
  const int quad = lane >> 4;
  const int cl = lane & 15;

  // XCD-affine swizzle, grid (8,64): f = by*8+bx; xcd = f&7; qp = (f>>3)&7;
  // bh = xcd*8 + (f>>6). All 8 q-pair blocks of one (b,h) on one XCD. Bijective:
  // 512 = 8 xcd x 8 qp x 8 bh-per-xcd.
  const int f = blockIdx.y * 8 + blockIdx.x;
  const int xcd = f & 7;
  const int u = f >> 3;
  const int qp = u & 7;
  const int bh = xcd * 8 + (u >> 3);
  const int b = bh >> 4;
  const int h = bh & 15;
  u16* Pw = smem + 16384 + wave * (32 * 72);  // P[q=32][kv=64], stride 72

  const u16* qbase = qkv + (size_t)(b * SEQ) * 3072 + h * 64;
  const u16* kbase = qbase + 1024;
  const u16* vbase = vt + (size_t)bh * 64 * SEQ;

  // all-ones bf16 A-frag (layout-independent)
  short8 ones8;
#pragma unroll
  for (int i = 0; i < 8; ++i) ones8[i] = (short)0x3F80;

  for (int half = 0; half < 2; ++half) {
    const int q0 = (qp * 2 + half) * 128;

    // all LDS reads of the prior half (or nothing, half=0) done before Q overwrite
    __syncthreads();
    // ---- stage Q tile (128 x 64) swizzled into Ks region ----
#pragma unroll
    for (int p = 0; p < 4; ++p) {
      const int g = (wave * 4 + p) * 64 + lane;
      const int r = g >> 3;
      const int c = (g & 7) ^ (r & 7);
      async16(qbase + (size_t)(q0 + r) * 3072 + c * 8, smem + g * 8);
    }
    __syncthreads();
    short8 qf[2][2];  // B-frag [n=q][k=d]
#pragma unroll
    for (int ng = 0; ng < 2; ++ng)
#pragma unroll
      for (int kc = 0; kc < 2; ++kc) {
        const int row = wave * 32 + ng * 16 + cl;
        qf[ng][kc] = *(const short8*)(smem + row * 64 + (((kc * 4 + quad) ^ (cl & 7)) * 8));
      }

    floatx4 O[4][2];   // [d-group][q-group]
    floatx4 Ol[2];     // l accumulator (rows replicated; any reg = l[q=cl])
#pragma unroll
    for (int mg = 0; mg < 4; ++mg)
#pragma unroll
      for (int ng = 0; ng < 2; ++ng) O[mg][ng] = (floatx4){0.f, 0.f, 0.f, 0.f};
#pragma unroll
    for (int ng = 0; ng < 2; ++ng) Ol[ng] = (floatx4){0.f, 0.f, 0.f, 0.f};

    for (int kt = 0; kt < SEQ / 128; ++kt) {
      const int k0 = kt * 128;
      __syncthreads();  // previous tile consumed (iter 0: qf loaded)
      const u16* kb = kbase + (size_t)k0 * 3072;
#pragma unroll
      for (int p = 0; p < 2; ++p) {
        const int g = wave * 128 + p * 64 + lane;
        const int rk = g >> 3;
        const int ck = (g & 7) ^ (rk & 7);
        async16(kb + (size_t)rk * 3072 + ck * 8, Ks + g * 8);
        const int rv = g >> 4;
        const int cv = (g & 15) ^ (rv & 15);
        async16(vbase + (size_t)rv * SEQ + k0 + cv * 8, Vs + g * 8);
      }
      __syncthreads();  // all tiles landed (vmcnt drained at barrier)

#pragma unroll
      for (int s = 0; s < 2; ++s) {
        // ---- S^T = K Q^T ----
        floatx4 Sc[4][2];
#pragma unroll
        for (int mg = 0; mg < 4; ++mg)
#pragma unroll
          for (int ng = 0; ng < 2; ++ng) Sc[mg][ng] = (floatx4){0.f, 0.f, 0.f, 0.f};
#pragma unroll
        for (int kc = 0; kc < 2; ++kc) {
          short8 kf[4];
#pragma unroll
          for (int mg = 0; mg < 4; ++mg) {
            const int row = s * 64 + mg * 16 + cl;
            kf[mg] = *(const short8*)(Ks + row * 64 + (((kc * 4 + quad) ^ (cl & 7)) * 8));
          }
#pragma unroll
          for (int mg = 0; mg < 4; ++mg)
#pragma unroll
            for (int ng = 0; ng < 2; ++ng)
              Sc[mg][ng] = __builtin_amdgcn_mfma_f32_16x16x32_bf16(kf[mg], qf[ng][kc], Sc[mg][ng], 0, 0, 0);
        }

        // ---- no-max softmax: P = 2^S (Q prescaled); l via MFMA below ----
#pragma unroll
        for (int ng = 0; ng < 2; ++ng)
#pragma unroll
          for (int mg = 0; mg < 4; ++mg)
#pragma unroll
            for (int r = 0; r < 4; ++r)
              Sc[mg][ng][r] = exp2_fast(Sc[mg][ng][r]);

        // ---- P pack (truncating perm) + b64 store, wave-private ----
#pragma unroll
        for (int mg = 0; mg < 4; ++mg)
#pragma unroll
          for (int ng = 0; ng < 2; ++ng) {
            const unsigned int lo = pack_trunc(Sc[mg][ng][0], Sc[mg][ng][1]);
            const unsigned int hi = pack_trunc(Sc[mg][ng][2], Sc[mg][ng][3]);
            *(uint2*)(Pw + (ng * 16 + cl) * 72 + mg * 16 + quad * 4) = make_uint2(lo, hi);
          }

        // ---- O^T += V^T P^T ; l += ones * P^T (matrix-pipe row-sum) ----
#pragma unroll
        for (int kc = 0; kc < 2; ++kc) {
          short8 pf[2], vf[4];
#pragma unroll
          for (int ng = 0; ng < 2; ++ng)
            pf[ng] = *(const short8*)(Pw + (ng * 16 + cl) * 72 + kc * 32 + quad * 8);
#pragma unroll
          for (int mg = 0; mg < 4; ++mg) {
            const int row = mg * 16 + cl;
            vf[mg] = *(const short8*)(Vs + row * 128 + (((s * 8 + kc * 4 + quad) ^ (cl & 15)) * 8));
          }
#pragma unroll
          for (int mg = 0; mg < 4; ++mg)
#pragma unroll
            for (int ng = 0; ng < 2; ++ng)
              O[mg][ng] = __builtin_amdgcn_mfma_f32_16x16x32_bf16(vf[mg], pf[ng], O[mg][ng], 0, 0, 0);
#pragma unroll
          for (int ng = 0; ng < 2; ++ng)
            Ol[ng] = __builtin_amdgcn_mfma_f32_16x16x32_bf16(ones8, pf[ng], Ol[ng], 0, 0, 0);
        }
      }
    }

    // ---- epilogue: O^T[d][q] / l -> out[q][h*64+d] ----
#pragma unroll
    for (int ng = 0; ng < 2; ++ng) {
      const float inv = 1.0f / Ol[ng][0];
      const int qrow = q0 + wave * 32 + ng * 16 + cl;
      u16* od = outp + (size_t)(b * SEQ + qrow) * EDIM + h * 64;
#pragma unroll
      for (int mg = 0; mg < 4; ++mg) {
        const unsigned int lo = (unsigned int)f2bf(O[mg][ng][0] * inv) |
                                ((unsigned int)f2bf(O[mg][ng][1] * inv) << 16);
        const unsigned int hi = (unsigned int)f2bf(O[mg][ng][2] * inv) |
                                ((unsigned int)f2bf(O[mg][ng][3] * inv) << 16);
        *(uint2*)(od + mg * 16 + quad * 4) = make_uint2(lo, hi);
      }
    }
  }
}

// ---------------- launcher ----------------
extern "C" void kernel_launch(void* const* d_in, const int* in_sizes, int n_in,
                              void* d_out, int out_size, void* d_ws, size_t ws_size,
                              hipStream_t stream) {
  const float* x    = (const float*)d_in[0];
  const float* qkvw = (const float*)d_in[1];
  const float* fcw  = (const float*)d_in[2];
  const float* fcb  = (const float*)d_in[3];
  const float* ln1g = (const float*)d_in[4];
  const float* ln1b = (const float*)d_in[5];
  const float* ln2g = (const float*)d_in[6];
  const float* ln2b = (const float*)d_in[7];
  const float* w1   = (const float*)d_in[8];
  const float* b1   = (const float*)d_in[9];
  const float* w2   = (const float*)d_in[10];
  const float* b2   = (const float*)d_in[11];

  char* ws = (char*)d_ws;
  size_t off = 0;
  u16* wqkv = (u16*)(ws + off); off += (size_t)3 * EDIM * EDIM * 2;   // 6 MB
  u16* wfc  = (u16*)(ws + off); off += (size_t)EDIM * EDIM * 2;       // 2 MB
  u16* w1b  = (u16*)(ws + off); off += (size_t)MLPD * EDIM * 2;       // 8 MB
  u16* w2b  = (u16*)(ws + off); off += (size_t)EDIM * MLPD * 2;       // 8 MB
  u16* hbuf = (u16*)(ws + off); off += (size_t)ROWS * EDIM * 2;       // 16 MB
  u16* aout = (u16*)(ws + off); off += (size_t)ROWS * EDIM * 2;       // 16 MB
  float* x2 = (float*)(ws + off); off += (size_t)ROWS * EDIM * 4;     // 32 MB
  u16* qkvb = (u16*)(ws + off); off += (size_t)ROWS * 3 * EDIM * 2;   // 48 MB (bf16)
  u16* vtb  = (u16*)(ws + off); off += (size_t)ROWS * EDIM * 2;       // 16 MB
  u16* hmlp = qkvb;  // reuse qkvb+vtb (64 MB) for MLP hidden after attention

  // all weights -> bf16 in one launch
  cvt_all<<<12288, 256, 0, stream>>>(qkvw, wqkv, 3 * EDIM * EDIM,
                                     fcw, wfc, EDIM * EDIM,
                                     w1, w1b, MLPD * EDIM,
                                     w2, w2b);

  // attention sublayer
  ln_bf16<<<ROWS, 256, 0, stream>>>(x, ln1g, ln1b, hbuf);
  gemm_bt<5><<<dim3(24, 32), 512, 0, stream>>>(hbuf, wqkv, qkvb, nullptr, nullptr,
                                               ROWS, 3 * EDIM, EDIM);
  vtrans<<<dim3(SEQ / 64, 64), 256, 0, stream>>>(qkvb, vtb);
  attn3<<<dim3(8, 64), 256, 0, stream>>>(qkvb, vtb, aout);
  gemm_bt<1, 128, 128><<<dim3(8, 64), 512, 0, stream>>>(aout, wfc, x2, fcb, x,
                                                        ROWS, EDIM, EDIM);
  // MLP sublayer
  ln_bf16<<<ROWS, 256, 0, stream>>>(x2, ln2g, ln2b, hbuf);
  gemm_bt<2><<<dim3(32, 32), 512, 0, stream>>>(hbuf, w1b, hmlp, b1, nullptr,
                                               ROWS, MLPD, EDIM);
  gemm_bt<3, 128, 128><<<dim3(8, 64), 512, 0, stream>>>(hmlp, w2b, (float*)d_out, b2, x2,
                                                        ROWS, EDIM, MLPD);
}

// Round 10
// 488.125 us; speedup vs baseline: 1.0223x; 1.0223x over previous
//
#include <hip/hip_runtime.h>
#include <cstdint>
#include <cmath>

// Problem constants
#define EDIM 1024
#define SEQ 2048
#define BATCH 4
#define NHEAD 16
#define HDIM 64
#define MLPD 4096
#define ROWS 8192  // BATCH*SEQ

typedef unsigned short u16;
typedef __attribute__((ext_vector_type(8))) short short8;   // 8 bf16 = 4 VGPRs (MFMA A/B frag)
typedef __attribute__((ext_vector_type(4))) float floatx4;  // MFMA C/D frag

#define AS1 __attribute__((address_space(1)))
#define AS3 __attribute__((address_space(3)))

// exp(s*0.125) = 2^(s*0.125*log2e); fold scale into Q at GEMM epilogue
#define Q_SCALE 0.18033688011112042f

__device__ __forceinline__ void async16(const void* g, void* l) {
  // 16B-wide global->LDS DMA; LDS dest is wave-uniform base + lane*16
  __builtin_amdgcn_global_load_lds((AS1 void*)g, (AS3 void*)l, 16, 0, 0);
}

__device__ __forceinline__ u16 f2bf(float f) {  // RNE float->bf16
  union { float f; unsigned int u; } v; v.f = f;
  unsigned int u = v.u;
  u += 0x7fffu + ((u >> 16) & 1u);
  return (u16)(u >> 16);
}

__device__ __forceinline__ unsigned int u32of(float f) {
  union { float f; unsigned int u; } v; v.f = f; return v.u;
}

// pack hi16(a)|hi16(b)<<16 in one v_perm_b32 (truncating f32->bf16 pair)
__device__ __forceinline__ unsigned int pack_trunc(float a, float b) {
  return __builtin_amdgcn_perm(u32of(b), u32of(a), 0x07060302u);
}

// native v_exp_f32: computes 2^x
__device__ __forceinline__ float exp2_fast(float x) {
  return __builtin_amdgcn_exp2f(x);
}

// fast GELU (tanh form), ~12 VALU ops, no libm
__device__ __forceinline__ float gelu_f(float x) {
  const float y = 0.7978845608028654f * (x + 0.044715f * x * x * x);
  // tanh(y) = 1 - 2/(1 + 2^(y*2*log2(e)))
  const float e = exp2_fast(y * 2.885390081777927f);
  const float t = 1.0f - 2.0f * __builtin_amdgcn_rcpf(1.0f + e);
  return 0.5f * x * (1.0f + t);
}

// ---------------- all-weights fp32 -> bf16 convert (one launch) ----------------
// Region boundaries are multiples of 1024 elements -> no intra-block divergence.
__global__ __launch_bounds__(256) void cvt_all(const float* __restrict__ a, u16* __restrict__ oa, int na,
                                               const float* __restrict__ b, u16* __restrict__ ob, int nb,
                                               const float* __restrict__ c, u16* __restrict__ oc, int nc,
                                               const float* __restrict__ d, u16* __restrict__ od) {
  int i = (blockIdx.x * 256 + threadIdx.x) * 4;
  const float* src;
  u16* dst;
  if (i < na) { src = a; dst = oa; }
  else if ((i -= na) < nb) { src = b; dst = ob; }
  else if ((i -= nb) < nc) { src = c; dst = oc; }
  else { i -= nc; src = d; dst = od; }
  const float4 v = *(const float4*)(src + i);
  dst[i + 0] = f2bf(v.x); dst[i + 1] = f2bf(v.y);
  dst[i + 2] = f2bf(v.z); dst[i + 3] = f2bf(v.w);
}

// ---------------- LayerNorm (row of 1024) -> bf16 ----------------
__global__ __launch_bounds__(256) void ln_bf16(const float* __restrict__ x,
                                               const float* __restrict__ g,
                                               const float* __restrict__ bta,
                                               u16* __restrict__ outp) {
  const int row = blockIdx.x;
  const int tid = threadIdx.x;
  const float4 v = *(const float4*)(x + (size_t)row * EDIM + tid * 4);
  float s = v.x + v.y + v.z + v.w;
  float ss = v.x * v.x + v.y * v.y + v.z * v.z + v.w * v.w;
#pragma unroll
  for (int o = 1; o < 64; o <<= 1) {
    s += __shfl_xor(s, o);
    ss += __shfl_xor(ss, o);
  }
  __shared__ float red[8];
  const int wave = tid >> 6, lane = tid & 63;
  if (lane == 0) { red[wave] = s; red[4 + wave] = ss; }
  __syncthreads();
  s = red[0] + red[1] + red[2] + red[3];
  ss = red[4] + red[5] + red[6] + red[7];
  const float mu = s * (1.0f / 1024.0f);
  const float var = ss * (1.0f / 1024.0f) - mu * mu;
  const float inv = rsqrtf(var + 1e-5f);
  const float4 gv = *(const float4*)(g + tid * 4);
  const float4 bv = *(const float4*)(bta + tid * 4);
  u16* od = outp + (size_t)row * EDIM + tid * 4;
  od[0] = f2bf((v.x - mu) * inv * gv.x + bv.x);
  od[1] = f2bf((v.y - mu) * inv * gv.y + bv.y);
  od[2] = f2bf((v.z - mu) * inv * gv.z + bv.z);
  od[3] = f2bf((v.w - mu) * inv * gv.w + bv.w);
}

// ---------------- NT GEMM (proven 2-barrier structure): BMx128, BKx, 8 waves ------
// T1 XCD-affine remap (proven R5: 508->483): all nx col-blocks of one row-panel
// time-adjacent on ONE XCD so the shared A-panel hits that XCD's L2.
// Bijective for gridDim.y%8==0.
// BK=128 (proven R7: 483->480) for the grid-limited 2-block/CU GEMMs (fc, w2):
// halves exposed drain-barrier events at equal residency.
// EPI: 0 = store fp32
//      1/3 = fp32 store of (acc + bias[col] + res[idx])
//      2 = bf16 store of gelu(acc + bias[col])
//      4 = bf16 store of acc
//      5 = bf16 store of acc * (col<1024 ? Q_SCALE : 1)  (qkv GEMM, prescaled Q)
template <int EPI, int BM = 256, int BK = 64>
__global__ __launch_bounds__(512) void gemm_bt(const u16* __restrict__ A,
                                               const u16* __restrict__ Bw,
                                               void* __restrict__ Cout,
                                               const float* __restrict__ bias,
                                               const float* __restrict__ res,
                                               int M, int N, int K) {
  constexpr int IB = BM / 64;        // acc rows per wave: 256->4, 128->2
  constexpr int WROWS = BM / 4;      // rows per wave band: 256->64, 128->32
  constexpr int CPR = BK / 8;        // 16B chunks per row: 8 (BK=64) / 16 (BK=128)
  constexpr int ROWSP = 512 / CPR;   // rows staged per pass: 64 / 32
  constexpr int PA = BM / ROWSP;     // A staging passes
  constexpr int PB = 128 / ROWSP;    // B staging passes
  constexpr int S = BK / 32;         // k sub-steps per tile: 2 / 4
  __shared__ __align__(16) u16 As[BM * BK];
  __shared__ __align__(16) u16 Bs[128 * BK];
  const int tid = threadIdx.x;
  const int lane = tid & 63;
  const int wave = tid >> 6;      // 0..7
  const int quad = lane >> 4;
  const int cl = lane & 15;

  // ---- T1: XCD-affine bijective block remap (requires gridDim.y % 8 == 0) ----
  const int nx = gridDim.x;
  const int f = blockIdx.y * nx + blockIdx.x;   // dispatch-linear id
  const int xcd = f & 7;                        // HW round-robin XCD
  const int uu = f >> 3;
  const int rows_per = gridDim.y >> 3;          // row-panels per XCD
  const int bxy = xcd * rows_per + uu / nx;     // row-panel (col-blocks adjacent)
  const int bxx = uu % nx;                      // col-block

  const int row0 = bxy * BM;
  const int col0 = bxx * 128;
  const int wm = wave >> 1;       // 0..3: WROWS-row band
  const int wn = wave & 1;        // 0..1: 64-col band

  floatx4 acc[IB][4];
#pragma unroll
  for (int i = 0; i < IB; ++i)
#pragma unroll
    for (int j = 0; j < 4; ++j) acc[i][j] = (floatx4){0.f, 0.f, 0.f, 0.f};

  // staging: chunk c = p*512 + tid; row = p*ROWSP + (tid/CPR); LDS slot = tid%CPR;
  // global chunk gc = (tid%CPR) ^ (row&7)  (p-independent since ROWSP%8==0).
  const int trow = tid / CPR;
  const int gc = (tid % CPR) ^ (trow & 7);
  const u16* Ath = A + (size_t)(row0 + trow) * K + gc * 8;
  const u16* Bth = Bw + (size_t)(col0 + trow) * K + gc * 8;
  u16* lA = As + tid * 8;                  // + p*4096
  u16* lB = Bs + tid * 8;
  const size_t pstride = (size_t)ROWSP * K;

  for (int k0 = 0; k0 < K; k0 += BK) {
    __syncthreads();
#pragma unroll
    for (int p = 0; p < PA; ++p)
      async16(Ath + p * pstride + k0, lA + p * 4096);
#pragma unroll
    for (int p = 0; p < PB; ++p)
      async16(Bth + p * pstride + k0, lB + p * 4096);
    __syncthreads();
#pragma unroll
    for (int s = 0; s < S; ++s) {
      const int ko = ((s * 4 + quad) ^ (cl & 7)) * 8;
      short8 af[IB], bfr[4];
#pragma unroll
      for (int i = 0; i < IB; ++i)
        af[i] = *(const short8*)(As + (wm * WROWS + i * 16 + cl) * BK + ko);
#pragma unroll
      for (int j = 0; j < 4; ++j)
        bfr[j] = *(const short8*)(Bs + (wn * 64 + j * 16 + cl) * BK + ko);
#pragma unroll
      for (int i = 0; i < IB; ++i)
#pragma unroll
        for (int j = 0; j < 4; ++j)
          acc[i][j] = __builtin_amdgcn_mfma_f32_16x16x32_bf16(af[i], bfr[j], acc[i][j], 0, 0, 0);
    }
  }

  const float qscale = (EPI == 5 && col0 < 1024) ? Q_SCALE : 1.0f;
#pragma unroll
  for (int i = 0; i < IB; ++i) {
#pragma unroll
    for (int r = 0; r < 4; ++r) {
      const int row = row0 + wm * WROWS + i * 16 + quad * 4 + r;
#pragma unroll
      for (int j = 0; j < 4; ++j) {
        const int col = col0 + wn * 64 + j * 16 + cl;
        const size_t idx = (size_t)row * N + col;
        float v = acc[i][j][r];
        if (EPI == 0) {
          ((float*)Cout)[idx] = v;
        } else if (EPI == 1 || EPI == 3) {
          ((float*)Cout)[idx] = v + bias[col] + res[idx];
        } else if (EPI == 2) {
          ((u16*)Cout)[idx] = f2bf(gelu_f(v + bias[col]));
        } else if (EPI == 4) {
          ((u16*)Cout)[idx] = f2bf(v);
        } else if (EPI == 5) {
          ((u16*)Cout)[idx] = f2bf(v * qscale);
        }
      }
    }
  }
}

// ---------------- V transpose: qkv bf16 [tok][3072] -> vt[b,h][d][s] bf16 ----------------
__global__ __launch_bounds__(256) void vtrans(const u16* __restrict__ qkv,
                                              u16* __restrict__ vt) {
  __shared__ unsigned int T[64 * 65];
  const int tid = threadIdx.x;
  const int bh = blockIdx.y;
  const int b = bh >> 4;
  const int h = bh & 15;
  const int s0 = blockIdx.x * 64;
#pragma unroll
  for (int pp = 0; pp < 2; ++pp) {
    const int g = pp * 256 + tid;
    const int r = g >> 3;
    const int d0 = (g & 7) * 8;
    const u16* src = qkv + (size_t)(b * SEQ + s0 + r) * 3072 + 2048 + h * 64 + d0;
    short8 v = *(const short8*)src;
#pragma unroll
    for (int i = 0; i < 8; ++i) T[(d0 + i) * 65 + r] = (u16)v[i];
  }
  __syncthreads();
#pragma unroll
  for (int pp = 0; pp < 2; ++pp) {
    const int g = pp * 256 + tid;
    const int d = g >> 3;
    const int sc = (g & 7) * 8;
    short8 v;
#pragma unroll
    for (int i = 0; i < 8; ++i) v[i] = (short)(u16)T[d * 65 + sc + i];
    *(short8*)(vt + ((size_t)bh * 64 + d) * SEQ + s0 + sc) = v;
  }
}

// ---------------- MFMA flash attention v3.1 (REVERTED to proven R8 text) ----------
// v3.1 (proven R8: attn 112.8->104.3): l computed on the MATRIX pipe via
// mfma(A=ones, B=pf), reusing the PV B-fragments. R9's q-pair merge (v3.2) was a
// wash (tail removal == occupancy-cap loss; attn3 is NOT occupancy-bound) and is
// reverted.
__global__ __launch_bounds__(256, 4) void attn3(const u16* __restrict__ qkv,
                                                const u16* __restrict__ vt,
                                                u16* __restrict__ outp) {
  __shared__ __align__(16) u16 smem[8192 + 8192 + 4 * 32 * 72];  // Ks | Vs | P (51.2 KB)
  u16* Ks = smem;            // [128 kv][64 d], chunk-swizzled ^(row&7)
  u16* Vs = smem + 8192;     // [64 d][128 kv], chunk-swizzled ^(row&15)
  const int tid = threadIdx.x;
  const int lane = tid & 63;
  const int wave = tid >> 6;
  const int quad = lane >> 4;
  const int cl = lane & 15;

  // XCD-affine swizzle: all 16 q-blocks of one (b,h) on one XCD, adjacent in time
  const int f = blockIdx.y * 16 + blockIdx.x;
  const int xcd = f & 7;
  const int u = f >> 3;
  const int qi = u & 15;
  const int bh = xcd * 8 + (u >> 4);
  const int b = bh >> 4;
  const int h = bh & 15;
  const int q0 = qi * 128;
  u16* Pw = smem + 16384 + wave * (32 * 72);  // P[q=32][kv=64], stride 72

  const u16* qbase = qkv + (size_t)(b * SEQ) * 3072 + h * 64;
  const u16* kbase = qbase + 1024;
  const u16* vbase = vt + (size_t)bh * 64 * SEQ;

  // ---- stage Q tile (128 x 64) swizzled into Ks region ----
#pragma unroll
  for (int p = 0; p < 4; ++p) {
    const int g = (wave * 4 + p) * 64 + lane;
    const int r = g >> 3;
    const int c = (g & 7) ^ (r & 7);
    async16(qbase + (size_t)(q0 + r) * 3072 + c * 8, smem + g * 8);
  }
  __syncthreads();
  short8 qf[2][2];  // B-frag [n=q][k=d]
#pragma unroll
  for (int ng = 0; ng < 2; ++ng)
#pragma unroll
    for (int kc = 0; kc < 2; ++kc) {
      const int row = wave * 32 + ng * 16 + cl;
      qf[ng][kc] = *(const short8*)(smem + row * 64 + (((kc * 4 + quad) ^ (cl & 7)) * 8));
    }

  // all-ones bf16 A-frag (layout-independent)
  short8 ones8;
#pragma unroll
  for (int i = 0; i < 8; ++i) ones8[i] = (short)0x3F80;

  floatx4 O[4][2];   // [d-group][q-group]
  floatx4 Ol[2];     // l accumulator (rows replicated; any reg = l[q=cl])
#pragma unroll
  for (int mg = 0; mg < 4; ++mg)
#pragma unroll
    for (int ng = 0; ng < 2; ++ng) O[mg][ng] = (floatx4){0.f, 0.f, 0.f, 0.f};
#pragma unroll
  for (int ng = 0; ng < 2; ++ng) Ol[ng] = (floatx4){0.f, 0.f, 0.f, 0.f};

  for (int kt = 0; kt < SEQ / 128; ++kt) {
    const int k0 = kt * 128;
    __syncthreads();  // previous tile consumed (iter 0: qf loaded)
    const u16* kb = kbase + (size_t)k0 * 3072;
#pragma unroll
    for (int p = 0; p < 2; ++p) {
      const int g = wave * 128 + p * 64 + lane;
      const int rk = g >> 3;
      const int ck = (g & 7) ^ (rk & 7);
      async16(kb + (size_t)rk * 3072 + ck * 8, Ks + g * 8);
      const int rv = g >> 4;
      const int cv = (g & 15) ^ (rv & 15);
      async16(vbase + (size_t)rv * SEQ + k0 + cv * 8, Vs + g * 8);
    }
    __syncthreads();  // all tiles landed (vmcnt drained at barrier)

#pragma unroll
    for (int s = 0; s < 2; ++s) {
      // ---- S^T = K Q^T ----
      floatx4 Sc[4][2];
#pragma unroll
      for (int mg = 0; mg < 4; ++mg)
#pragma unroll
        for (int ng = 0; ng < 2; ++ng) Sc[mg][ng] = (floatx4){0.f, 0.f, 0.f, 0.f};
#pragma unroll
      for (int kc = 0; kc < 2; ++kc) {
        short8 kf[4];
#pragma unroll
        for (int mg = 0; mg < 4; ++mg) {
          const int row = s * 64 + mg * 16 + cl;
          kf[mg] = *(const short8*)(Ks + row * 64 + (((kc * 4 + quad) ^ (cl & 7)) * 8));
        }
#pragma unroll
        for (int mg = 0; mg < 4; ++mg)
#pragma unroll
          for (int ng = 0; ng < 2; ++ng)
            Sc[mg][ng] = __builtin_amdgcn_mfma_f32_16x16x32_bf16(kf[mg], qf[ng][kc], Sc[mg][ng], 0, 0, 0);
      }

      // ---- no-max softmax: P = 2^S (Q prescaled); l via MFMA below ----
#pragma unroll
      for (int ng = 0; ng < 2; ++ng)
#pragma unroll
        for (int mg = 0; mg < 4; ++mg)
#pragma unroll
          for (int r = 0; r < 4; ++r)
            Sc[mg][ng][r] = exp2_fast(Sc[mg][ng][r]);

      // ---- P pack (truncating perm) + b64 store, wave-private ----
#pragma unroll
      for (int mg = 0; mg < 4; ++mg)
#pragma unroll
        for (int ng = 0; ng < 2; ++ng) {
          const unsigned int lo = pack_trunc(Sc[mg][ng][0], Sc[mg][ng][1]);
          const unsigned int hi = pack_trunc(Sc[mg][ng][2], Sc[mg][ng][3]);
          *(uint2*)(Pw + (ng * 16 + cl) * 72 + mg * 16 + quad * 4) = make_uint2(lo, hi);
        }

      // ---- O^T += V^T P^T ; l += ones * P^T (matrix-pipe row-sum) ----
#pragma unroll
      for (int kc = 0; kc < 2; ++kc) {
        short8 pf[2], vf[4];
#pragma unroll
        for (int ng = 0; ng < 2; ++ng)
          pf[ng] = *(const short8*)(Pw + (ng * 16 + cl) * 72 + kc * 32 + quad * 8);
#pragma unroll
        for (int mg = 0; mg < 4; ++mg) {
          const int row = mg * 16 + cl;
          vf[mg] = *(const short8*)(Vs + row * 128 + (((s * 8 + kc * 4 + quad) ^ (cl & 15)) * 8));
        }
#pragma unroll
        for (int mg = 0; mg < 4; ++mg)
#pragma unroll
          for (int ng = 0; ng < 2; ++ng)
            O[mg][ng] = __builtin_amdgcn_mfma_f32_16x16x32_bf16(vf[mg], pf[ng], O[mg][ng], 0, 0, 0);
#pragma unroll
        for (int ng = 0; ng < 2; ++ng)
          Ol[ng] = __builtin_amdgcn_mfma_f32_16x16x32_bf16(ones8, pf[ng], Ol[ng], 0, 0, 0);
      }
    }
  }

  // ---- epilogue: O^T[d][q] / l -> out[q][h*64+d] ----
#pragma unroll
  for (int ng = 0; ng < 2; ++ng) {
    const float inv = 1.0f / Ol[ng][0];
    const int qrow = q0 + wave * 32 + ng * 16 + cl;
    u16* od = outp + (size_t)(b * SEQ + qrow) * EDIM + h * 64;
#pragma unroll
    for (int mg = 0; mg < 4; ++mg) {
      const unsigned int lo = (unsigned int)f2bf(O[mg][ng][0] * inv) |
                              ((unsigned int)f2bf(O[mg][ng][1] * inv) << 16);
      const unsigned int hi = (unsigned int)f2bf(O[mg][ng][2] * inv) |
                              ((unsigned int)f2bf(O[mg][ng][3] * inv) << 16);
      *(uint2*)(od + mg * 16 + quad * 4) = make_uint2(lo, hi);
    }
  }
}

// ---------------- launcher ----------------
extern "C" void kernel_launch(void* const* d_in, const int* in_sizes, int n_in,
                              void* d_out, int out_size, void* d_ws, size_t ws_size,
                              hipStream_t stream) {
  const float* x    = (const float*)d_in[0];
  const float* qkvw = (const float*)d_in[1];
  const float* fcw  = (const float*)d_in[2];
  const float* fcb  = (const float*)d_in[3];
  const float* ln1g = (const float*)d_in[4];
  const float* ln1b = (const float*)d_in[5];
  const float* ln2g = (const float*)d_in[6];
  const float* ln2b = (const float*)d_in[7];
  const float* w1   = (const float*)d_in[8];
  const float* b1   = (const float*)d_in[9];
  const float* w2   = (const float*)d_in[10];
  const float* b2   = (const float*)d_in[11];

  char* ws = (char*)d_ws;
  size_t off = 0;
  u16* wqkv = (u16*)(ws + off); off += (size_t)3 * EDIM * EDIM * 2;   // 6 MB
  u16* wfc  = (u16*)(ws + off); off += (size_t)EDIM * EDIM * 2;       // 2 MB
  u16* w1b  = (u16*)(ws + off); off += (size_t)MLPD * EDIM * 2;       // 8 MB
  u16* w2b  = (u16*)(ws + off); off += (size_t)EDIM * MLPD * 2;       // 8 MB
  u16* hbuf = (u16*)(ws + off); off += (size_t)ROWS * EDIM * 2;       // 16 MB
  u16* aout = (u16*)(ws + off); off += (size_t)ROWS * EDIM * 2;       // 16 MB
  float* x2 = (float*)(ws + off); off += (size_t)ROWS * EDIM * 4;     // 32 MB
  u16* qkvb = (u16*)(ws + off); off += (size_t)ROWS * 3 * EDIM * 2;   // 48 MB (bf16)
  u16* vtb  = (u16*)(ws + off); off += (size_t)ROWS * EDIM * 2;       // 16 MB
  u16* hmlp = qkvb;  // reuse qkvb+vtb (64 MB) for MLP hidden after attention

  // all weights -> bf16 in one launch
  cvt_all<<<12288, 256, 0, stream>>>(qkvw, wqkv, 3 * EDIM * EDIM,
                                     fcw, wfc, EDIM * EDIM,
                                     w1, w1b, MLPD * EDIM,
                                     w2, w2b);

  // attention sublayer
  ln_bf16<<<ROWS, 256, 0, stream>>>(x, ln1g, ln1b, hbuf);
  gemm_bt<5><<<dim3(24, 32), 512, 0, stream>>>(hbuf, wqkv, qkvb, nullptr, nullptr,
                                               ROWS, 3 * EDIM, EDIM);
  vtrans<<<dim3(SEQ / 64, 64), 256, 0, stream>>>(qkvb, vtb);
  attn3<<<dim3(16, 64), 256, 0, stream>>>(qkvb, vtb, aout);
  gemm_bt<1, 128, 128><<<dim3(8, 64), 512, 0, stream>>>(aout, wfc, x2, fcb, x,
                                                        ROWS, EDIM, EDIM);
  // MLP sublayer
  ln_bf16<<<ROWS, 256, 0, stream>>>(x2, ln2g, ln2b, hbuf);
  gemm_bt<2><<<dim3(32, 32), 512, 0, stream>>>(hbuf, w1b, hmlp, b1, nullptr,
                                               ROWS, MLPD, EDIM);
  gemm_bt<3, 128, 128><<<dim3(8, 64), 512, 0, stream>>>(hmlp, w2b, (float*)d_out, b2, x2,
                                                        ROWS, EDIM, MLPD);
}

// Round 11
// 476.121 us; speedup vs baseline: 1.0480x; 1.0252x over previous
//
#include <hip/hip_runtime.h>
#include <cstdint>
#include <cmath>

// Problem constants
#define EDIM 1024
#define SEQ 2048
#define BATCH 4
#define NHEAD 16
#define HDIM 64
#define MLPD 4096
#define ROWS 8192  // BATCH*SEQ

typedef unsigned short u16;
typedef __attribute__((ext_vector_type(8))) short short8;   // 8 bf16 = 4 VGPRs (MFMA A/B frag)
typedef __attribute__((ext_vector_type(4))) float floatx4;  // MFMA C/D frag

#define AS1 __attribute__((address_space(1)))
#define AS3 __attribute__((address_space(3)))

// exp(s*0.125) = 2^(s*0.125*log2e); fold scale into Q at GEMM epilogue
#define Q_SCALE 0.18033688011112042f

__device__ __forceinline__ void async16(const void* g, void* l) {
  // 16B-wide global->LDS DMA; LDS dest is wave-uniform base + lane*16
  __builtin_amdgcn_global_load_lds((AS1 void*)g, (AS3 void*)l, 16, 0, 0);
}

__device__ __forceinline__ u16 f2bf(float f) {  // RNE float->bf16
  union { float f; unsigned int u; } v; v.f = f;
  unsigned int u = v.u;
  u += 0x7fffu + ((u >> 16) & 1u);
  return (u16)(u >> 16);
}

__device__ __forceinline__ unsigned int u32of(float f) {
  union { float f; unsigned int u; } v; v.f = f; return v.u;
}

// pack hi16(a)|hi16(b)<<16 in one v_perm_b32 (truncating f32->bf16 pair)
__device__ __forceinline__ unsigned int pack_trunc(float a, float b) {
  return __builtin_amdgcn_perm(u32of(b), u32of(a), 0x07060302u);
}

// native v_exp_f32: computes 2^x
__device__ __forceinline__ float exp2_fast(float x) {
  return __builtin_amdgcn_exp2f(x);
}

// fast GELU (tanh form), ~12 VALU ops, no libm
__device__ __forceinline__ float gelu_f(float x) {
  const float y = 0.7978845608028654f * (x + 0.044715f * x * x * x);
  // tanh(y) = 1 - 2/(1 + 2^(y*2*log2(e)))
  const float e = exp2_fast(y * 2.885390081777927f);
  const float t = 1.0f - 2.0f * __builtin_amdgcn_rcpf(1.0f + e);
  return 0.5f * x * (1.0f + t);
}

// ---------------- all-weights fp32 -> bf16 convert (one launch) ----------------
// Region boundaries are multiples of 1024 elements -> no intra-block divergence.
__global__ __launch_bounds__(256) void cvt_all(const float* __restrict__ a, u16* __restrict__ oa, int na,
                                               const float* __restrict__ b, u16* __restrict__ ob, int nb,
                                               const float* __restrict__ c, u16* __restrict__ oc, int nc,
                                               const float* __restrict__ d, u16* __restrict__ od) {
  int i = (blockIdx.x * 256 + threadIdx.x) * 4;
  const float* src;
  u16* dst;
  if (i < na) { src = a; dst = oa; }
  else if ((i -= na) < nb) { src = b; dst = ob; }
  else if ((i -= nb) < nc) { src = c; dst = oc; }
  else { i -= nc; src = d; dst = od; }
  const float4 v = *(const float4*)(src + i);
  dst[i + 0] = f2bf(v.x); dst[i + 1] = f2bf(v.y);
  dst[i + 2] = f2bf(v.z); dst[i + 3] = f2bf(v.w);
}

// ---------------- LayerNorm (row of 1024) -> bf16 ----------------
__global__ __launch_bounds__(256) void ln_bf16(const float* __restrict__ x,
                                               const float* __restrict__ g,
                                               const float* __restrict__ bta,
                                               u16* __restrict__ outp) {
  const int row = blockIdx.x;
  const int tid = threadIdx.x;
  const float4 v = *(const float4*)(x + (size_t)row * EDIM + tid * 4);
  float s = v.x + v.y + v.z + v.w;
  float ss = v.x * v.x + v.y * v.y + v.z * v.z + v.w * v.w;
#pragma unroll
  for (int o = 1; o < 64; o <<= 1) {
    s += __shfl_xor(s, o);
    ss += __shfl_xor(ss, o);
  }
  __shared__ float red[8];
  const int wave = tid >> 6, lane = tid & 63;
  if (lane == 0) { red[wave] = s; red[4 + wave] = ss; }
  __syncthreads();
  s = red[0] + red[1] + red[2] + red[3];
  ss = red[4] + red[5] + red[6] + red[7];
  const float mu = s * (1.0f / 1024.0f);
  const float var = ss * (1.0f / 1024.0f) - mu * mu;
  const float inv = rsqrtf(var + 1e-5f);
  const float4 gv = *(const float4*)(g + tid * 4);
  const float4 bv = *(const float4*)(bta + tid * 4);
  u16* od = outp + (size_t)row * EDIM + tid * 4;
  od[0] = f2bf((v.x - mu) * inv * gv.x + bv.x);
  od[1] = f2bf((v.y - mu) * inv * gv.y + bv.y);
  od[2] = f2bf((v.z - mu) * inv * gv.z + bv.z);
  od[3] = f2bf((v.w - mu) * inv * gv.w + bv.w);
}

// ---------------- NT GEMM (proven 2-barrier structure): BMx128, BKx, 8 waves ------
// T1 XCD-affine remap (proven R5: 508->483): all nx col-blocks of one row-panel
// time-adjacent on ONE XCD so the shared A-panel hits that XCD's L2.
// Bijective for gridDim.y%8==0.
// BK=128 (proven R7: 483->480) for the grid-limited 2-block/CU GEMMs (fc, w2):
// halves exposed drain-barrier events at equal residency.
// BM=128/BK=64 for w1 (R11): grid (32,64)=2048 blocks at 4/CU (LDS 32KB,
// wave-limited) = exactly 2 full rounds -> eliminates w1's 256-block tail round
// at 1/CU (was 1024 blocks on 768 slots at 3/CU).
// EPI: 0 = store fp32
//      1/3 = fp32 store of (acc + bias[col] + res[idx])
//      2 = bf16 store of gelu(acc + bias[col])
//      4 = bf16 store of acc
//      5 = bf16 store of acc * (col<1024 ? Q_SCALE : 1)  (qkv GEMM, prescaled Q)
template <int EPI, int BM = 256, int BK = 64>
__global__ __launch_bounds__(512) void gemm_bt(const u16* __restrict__ A,
                                               const u16* __restrict__ Bw,
                                               void* __restrict__ Cout,
                                               const float* __restrict__ bias,
                                               const float* __restrict__ res,
                                               int M, int N, int K) {
  constexpr int IB = BM / 64;        // acc rows per wave: 256->4, 128->2
  constexpr int WROWS = BM / 4;      // rows per wave band: 256->64, 128->32
  constexpr int CPR = BK / 8;        // 16B chunks per row: 8 (BK=64) / 16 (BK=128)
  constexpr int ROWSP = 512 / CPR;   // rows staged per pass: 64 / 32
  constexpr int PA = BM / ROWSP;     // A staging passes
  constexpr int PB = 128 / ROWSP;    // B staging passes
  constexpr int S = BK / 32;         // k sub-steps per tile: 2 / 4
  __shared__ __align__(16) u16 As[BM * BK];
  __shared__ __align__(16) u16 Bs[128 * BK];
  const int tid = threadIdx.x;
  const int lane = tid & 63;
  const int wave = tid >> 6;      // 0..7
  const int quad = lane >> 4;
  const int cl = lane & 15;

  // ---- T1: XCD-affine bijective block remap (requires gridDim.y % 8 == 0) ----
  const int nx = gridDim.x;
  const int f = blockIdx.y * nx + blockIdx.x;   // dispatch-linear id
  const int xcd = f & 7;                        // HW round-robin XCD
  const int uu = f >> 3;
  const int rows_per = gridDim.y >> 3;          // row-panels per XCD
  const int bxy = xcd * rows_per + uu / nx;     // row-panel (col-blocks adjacent)
  const int bxx = uu % nx;                      // col-block

  const int row0 = bxy * BM;
  const int col0 = bxx * 128;
  const int wm = wave >> 1;       // 0..3: WROWS-row band
  const int wn = wave & 1;        // 0..1: 64-col band

  floatx4 acc[IB][4];
#pragma unroll
  for (int i = 0; i < IB; ++i)
#pragma unroll
    for (int j = 0; j < 4; ++j) acc[i][j] = (floatx4){0.f, 0.f, 0.f, 0.f};

  // staging: chunk c = p*512 + tid; row = p*ROWSP + (tid/CPR); LDS slot = tid%CPR;
  // global chunk gc = (tid%CPR) ^ (row&7)  (p-independent since ROWSP%8==0).
  const int trow = tid / CPR;
  const int gc = (tid % CPR) ^ (trow & 7);
  const u16* Ath = A + (size_t)(row0 + trow) * K + gc * 8;
  const u16* Bth = Bw + (size_t)(col0 + trow) * K + gc * 8;
  u16* lA = As + tid * 8;                  // + p*4096
  u16* lB = Bs + tid * 8;
  const size_t pstride = (size_t)ROWSP * K;

  for (int k0 = 0; k0 < K; k0 += BK) {
    __syncthreads();
#pragma unroll
    for (int p = 0; p < PA; ++p)
      async16(Ath + p * pstride + k0, lA + p * 4096);
#pragma unroll
    for (int p = 0; p < PB; ++p)
      async16(Bth + p * pstride + k0, lB + p * 4096);
    __syncthreads();
#pragma unroll
    for (int s = 0; s < S; ++s) {
      const int ko = ((s * 4 + quad) ^ (cl & 7)) * 8;
      short8 af[IB], bfr[4];
#pragma unroll
      for (int i = 0; i < IB; ++i)
        af[i] = *(const short8*)(As + (wm * WROWS + i * 16 + cl) * BK + ko);
#pragma unroll
      for (int j = 0; j < 4; ++j)
        bfr[j] = *(const short8*)(Bs + (wn * 64 + j * 16 + cl) * BK + ko);
#pragma unroll
      for (int i = 0; i < IB; ++i)
#pragma unroll
        for (int j = 0; j < 4; ++j)
          acc[i][j] = __builtin_amdgcn_mfma_f32_16x16x32_bf16(af[i], bfr[j], acc[i][j], 0, 0, 0);
    }
  }

  const float qscale = (EPI == 5 && col0 < 1024) ? Q_SCALE : 1.0f;
#pragma unroll
  for (int i = 0; i < IB; ++i) {
#pragma unroll
    for (int r = 0; r < 4; ++r) {
      const int row = row0 + wm * WROWS + i * 16 + quad * 4 + r;
#pragma unroll
      for (int j = 0; j < 4; ++j) {
        const int col = col0 + wn * 64 + j * 16 + cl;
        const size_t idx = (size_t)row * N + col;
        float v = acc[i][j][r];
        if (EPI == 0) {
          ((float*)Cout)[idx] = v;
        } else if (EPI == 1 || EPI == 3) {
          ((float*)Cout)[idx] = v + bias[col] + res[idx];
        } else if (EPI == 2) {
          ((u16*)Cout)[idx] = f2bf(gelu_f(v + bias[col]));
        } else if (EPI == 4) {
          ((u16*)Cout)[idx] = f2bf(v);
        } else if (EPI == 5) {
          ((u16*)Cout)[idx] = f2bf(v * qscale);
        }
      }
    }
  }
}

// ---------------- V transpose: qkv bf16 [tok][3072] -> vt[b,h][d][s] bf16 ----------------
__global__ __launch_bounds__(256) void vtrans(const u16* __restrict__ qkv,
                                              u16* __restrict__ vt) {
  __shared__ unsigned int T[64 * 65];
  const int tid = threadIdx.x;
  const int bh = blockIdx.y;
  const int b = bh >> 4;
  const int h = bh & 15;
  const int s0 = blockIdx.x * 64;
#pragma unroll
  for (int pp = 0; pp < 2; ++pp) {
    const int g = pp * 256 + tid;
    const int r = g >> 3;
    const int d0 = (g & 7) * 8;
    const u16* src = qkv + (size_t)(b * SEQ + s0 + r) * 3072 + 2048 + h * 64 + d0;
    short8 v = *(const short8*)src;
#pragma unroll
    for (int i = 0; i < 8; ++i) T[(d0 + i) * 65 + r] = (u16)v[i];
  }
  __syncthreads();
#pragma unroll
  for (int pp = 0; pp < 2; ++pp) {
    const int g = pp * 256 + tid;
    const int d = g >> 3;
    const int sc = (g & 7) * 8;
    short8 v;
#pragma unroll
    for (int i = 0; i < 8; ++i) v[i] = (short)(u16)T[d * 65 + sc + i];
    *(short8*)(vt + ((size_t)bh * 64 + d) * SEQ + s0 + sc) = v;
  }
}

// ---------------- MFMA flash attention v3.1 (proven best: R8/R10 103.4-104.3us) ----
// l computed on the MATRIX pipe via mfma(A=ones, B=pf), reusing the PV
// B-fragments. attn3 is dependency-chain-bound (MfmaUtil 30 + VALUBusy 42, both
// under cap); P-store (b64) and all b128 reads are AT their wave64 LDS aliasing
// floors -> bank-conflict counter is inherent cost, not a lever. FROZEN.
__global__ __launch_bounds__(256, 4) void attn3(const u16* __restrict__ qkv,
                                                const u16* __restrict__ vt,
                                                u16* __restrict__ outp) {
  __shared__ __align__(16) u16 smem[8192 + 8192 + 4 * 32 * 72];  // Ks | Vs | P (51.2 KB)
  u16* Ks = smem;            // [128 kv][64 d], chunk-swizzled ^(row&7)
  u16* Vs = smem + 8192;     // [64 d][128 kv], chunk-swizzled ^(row&15)
  const int tid = threadIdx.x;
  const int lane = tid & 63;
  const int wave = tid >> 6;
  const int quad = lane >> 4;
  const int cl = lane & 15;

  // XCD-affine swizzle: all 16 q-blocks of one (b,h) on one XCD, adjacent in time
  const int f = blockIdx.y * 16 + blockIdx.x;
  const int xcd = f & 7;
  const int u = f >> 3;
  const int qi = u & 15;
  const int bh = xcd * 8 + (u >> 4);
  const int b = bh >> 4;
  const int h = bh & 15;
  const int q0 = qi * 128;
  u16* Pw = smem + 16384 + wave * (32 * 72);  // P[q=32][kv=64], stride 72

  const u16* qbase = qkv + (size_t)(b * SEQ) * 3072 + h * 64;
  const u16* kbase = qbase + 1024;
  const u16* vbase = vt + (size_t)bh * 64 * SEQ;

  // ---- stage Q tile (128 x 64) swizzled into Ks region ----
#pragma unroll
  for (int p = 0; p < 4; ++p) {
    const int g = (wave * 4 + p) * 64 + lane;
    const int r = g >> 3;
    const int c = (g & 7) ^ (r & 7);
    async16(qbase + (size_t)(q0 + r) * 3072 + c * 8, smem + g * 8);
  }
  __syncthreads();
  short8 qf[2][2];  // B-frag [n=q][k=d]
#pragma unroll
  for (int ng = 0; ng < 2; ++ng)
#pragma unroll
    for (int kc = 0; kc < 2; ++kc) {
      const int row = wave * 32 + ng * 16 + cl;
      qf[ng][kc] = *(const short8*)(smem + row * 64 + (((kc * 4 + quad) ^ (cl & 7)) * 8));
    }

  // all-ones bf16 A-frag (layout-independent)
  short8 ones8;
#pragma unroll
  for (int i = 0; i < 8; ++i) ones8[i] = (short)0x3F80;

  floatx4 O[4][2];   // [d-group][q-group]
  floatx4 Ol[2];     // l accumulator (rows replicated; any reg = l[q=cl])
#pragma unroll
  for (int mg = 0; mg < 4; ++mg)
#pragma unroll
    for (int ng = 0; ng < 2; ++ng) O[mg][ng] = (floatx4){0.f, 0.f, 0.f, 0.f};
#pragma unroll
  for (int ng = 0; ng < 2; ++ng) Ol[ng] = (floatx4){0.f, 0.f, 0.f, 0.f};

  for (int kt = 0; kt < SEQ / 128; ++kt) {
    const int k0 = kt * 128;
    __syncthreads();  // previous tile consumed (iter 0: qf loaded)
    const u16* kb = kbase + (size_t)k0 * 3072;
#pragma unroll
    for (int p = 0; p < 2; ++p) {
      const int g = wave * 128 + p * 64 + lane;
      const int rk = g >> 3;
      const int ck = (g & 7) ^ (rk & 7);
      async16(kb + (size_t)rk * 3072 + ck * 8, Ks + g * 8);
      const int rv = g >> 4;
      const int cv = (g & 15) ^ (rv & 15);
      async16(vbase + (size_t)rv * SEQ + k0 + cv * 8, Vs + g * 8);
    }
    __syncthreads();  // all tiles landed (vmcnt drained at barrier)

#pragma unroll
    for (int s = 0; s < 2; ++s) {
      // ---- S^T = K Q^T ----
      floatx4 Sc[4][2];
#pragma unroll
      for (int mg = 0; mg < 4; ++mg)
#pragma unroll
        for (int ng = 0; ng < 2; ++ng) Sc[mg][ng] = (floatx4){0.f, 0.f, 0.f, 0.f};
#pragma unroll
      for (int kc = 0; kc < 2; ++kc) {
        short8 kf[4];
#pragma unroll
        for (int mg = 0; mg < 4; ++mg) {
          const int row = s * 64 + mg * 16 + cl;
          kf[mg] = *(const short8*)(Ks + row * 64 + (((kc * 4 + quad) ^ (cl & 7)) * 8));
        }
#pragma unroll
        for (int mg = 0; mg < 4; ++mg)
#pragma unroll
          for (int ng = 0; ng < 2; ++ng)
            Sc[mg][ng] = __builtin_amdgcn_mfma_f32_16x16x32_bf16(kf[mg], qf[ng][kc], Sc[mg][ng], 0, 0, 0);
      }

      // ---- no-max softmax: P = 2^S (Q prescaled); l via MFMA below ----
#pragma unroll
      for (int ng = 0; ng < 2; ++ng)
#pragma unroll
        for (int mg = 0; mg < 4; ++mg)
#pragma unroll
          for (int r = 0; r < 4; ++r)
            Sc[mg][ng][r] = exp2_fast(Sc[mg][ng][r]);

      // ---- P pack (truncating perm) + b64 store, wave-private ----
#pragma unroll
      for (int mg = 0; mg < 4; ++mg)
#pragma unroll
        for (int ng = 0; ng < 2; ++ng) {
          const unsigned int lo = pack_trunc(Sc[mg][ng][0], Sc[mg][ng][1]);
          const unsigned int hi = pack_trunc(Sc[mg][ng][2], Sc[mg][ng][3]);
          *(uint2*)(Pw + (ng * 16 + cl) * 72 + mg * 16 + quad * 4) = make_uint2(lo, hi);
        }

      // ---- O^T += V^T P^T ; l += ones * P^T (matrix-pipe row-sum) ----
#pragma unroll
      for (int kc = 0; kc < 2; ++kc) {
        short8 pf[2], vf[4];
#pragma unroll
        for (int ng = 0; ng < 2; ++ng)
          pf[ng] = *(const short8*)(Pw + (ng * 16 + cl) * 72 + kc * 32 + quad * 8);
#pragma unroll
        for (int mg = 0; mg < 4; ++mg) {
          const int row = mg * 16 + cl;
          vf[mg] = *(const short8*)(Vs + row * 128 + (((s * 8 + kc * 4 + quad) ^ (cl & 15)) * 8));
        }
#pragma unroll
        for (int mg = 0; mg < 4; ++mg)
#pragma unroll
          for (int ng = 0; ng < 2; ++ng)
            O[mg][ng] = __builtin_amdgcn_mfma_f32_16x16x32_bf16(vf[mg], pf[ng], O[mg][ng], 0, 0, 0);
#pragma unroll
        for (int ng = 0; ng < 2; ++ng)
          Ol[ng] = __builtin_amdgcn_mfma_f32_16x16x32_bf16(ones8, pf[ng], Ol[ng], 0, 0, 0);
      }
    }
  }

  // ---- epilogue: O^T[d][q] / l -> out[q][h*64+d] ----
#pragma unroll
  for (int ng = 0; ng < 2; ++ng) {
    const float inv = 1.0f / Ol[ng][0];
    const int qrow = q0 + wave * 32 + ng * 16 + cl;
    u16* od = outp + (size_t)(b * SEQ + qrow) * EDIM + h * 64;
#pragma unroll
    for (int mg = 0; mg < 4; ++mg) {
      const unsigned int lo = (unsigned int)f2bf(O[mg][ng][0] * inv) |
                              ((unsigned int)f2bf(O[mg][ng][1] * inv) << 16);
      const unsigned int hi = (unsigned int)f2bf(O[mg][ng][2] * inv) |
                              ((unsigned int)f2bf(O[mg][ng][3] * inv) << 16);
      *(uint2*)(od + mg * 16 + quad * 4) = make_uint2(lo, hi);
    }
  }
}

// ---------------- launcher ----------------
extern "C" void kernel_launch(void* const* d_in, const int* in_sizes, int n_in,
                              void* d_out, int out_size, void* d_ws, size_t ws_size,
                              hipStream_t stream) {
  const float* x    = (const float*)d_in[0];
  const float* qkvw = (const float*)d_in[1];
  const float* fcw  = (const float*)d_in[2];
  const float* fcb  = (const float*)d_in[3];
  const float* ln1g = (const float*)d_in[4];
  const float* ln1b = (const float*)d_in[5];
  const float* ln2g = (const float*)d_in[6];
  const float* ln2b = (const float*)d_in[7];
  const float* w1   = (const float*)d_in[8];
  const float* b1   = (const float*)d_in[9];
  const float* w2   = (const float*)d_in[10];
  const float* b2   = (const float*)d_in[11];

  char* ws = (char*)d_ws;
  size_t off = 0;
  u16* wqkv = (u16*)(ws + off); off += (size_t)3 * EDIM * EDIM * 2;   // 6 MB
  u16* wfc  = (u16*)(ws + off); off += (size_t)EDIM * EDIM * 2;       // 2 MB
  u16* w1b  = (u16*)(ws + off); off += (size_t)MLPD * EDIM * 2;       // 8 MB
  u16* w2b  = (u16*)(ws + off); off += (size_t)EDIM * MLPD * 2;       // 8 MB
  u16* hbuf = (u16*)(ws + off); off += (size_t)ROWS * EDIM * 2;       // 16 MB
  u16* aout = (u16*)(ws + off); off += (size_t)ROWS * EDIM * 2;       // 16 MB
  float* x2 = (float*)(ws + off); off += (size_t)ROWS * EDIM * 4;     // 32 MB
  u16* qkvb = (u16*)(ws + off); off += (size_t)ROWS * 3 * EDIM * 2;   // 48 MB (bf16)
  u16* vtb  = (u16*)(ws + off); off += (size_t)ROWS * EDIM * 2;       // 16 MB
  u16* hmlp = qkvb;  // reuse qkvb+vtb (64 MB) for MLP hidden after attention

  // all weights -> bf16 in one launch
  cvt_all<<<12288, 256, 0, stream>>>(qkvw, wqkv, 3 * EDIM * EDIM,
                                     fcw, wfc, EDIM * EDIM,
                                     w1, w1b, MLPD * EDIM,
                                     w2, w2b);

  // attention sublayer
  ln_bf16<<<ROWS, 256, 0, stream>>>(x, ln1g, ln1b, hbuf);
  gemm_bt<5><<<dim3(24, 32), 512, 0, stream>>>(hbuf, wqkv, qkvb, nullptr, nullptr,
                                               ROWS, 3 * EDIM, EDIM);
  vtrans<<<dim3(SEQ / 64, 64), 256, 0, stream>>>(qkvb, vtb);
  attn3<<<dim3(16, 64), 256, 0, stream>>>(qkvb, vtb, aout);
  gemm_bt<1, 128, 128><<<dim3(8, 64), 512, 0, stream>>>(aout, wfc, x2, fcb, x,
                                                        ROWS, EDIM, EDIM);
  // MLP sublayer
  ln_bf16<<<ROWS, 256, 0, stream>>>(x2, ln2g, ln2b, hbuf);
  gemm_bt<2, 128><<<dim3(32, 64), 512, 0, stream>>>(hbuf, w1b, hmlp, b1, nullptr,
                                                    ROWS, MLPD, EDIM);
  gemm_bt<3, 128, 128><<<dim3(8, 64), 512, 0, stream>>>(hmlp, w2b, (float*)d_out, b2, x2,
                                                        ROWS, EDIM, MLPD);
}